// Round 10
// baseline (161.816 us; speedup 1.0000x reference)
//
#include <hip/hip_runtime.h>
#include <math.h>

typedef __attribute__((ext_vector_type(8))) short short8x;   // 8 x bf16 = 4 VGPRs
typedef __attribute__((ext_vector_type(4))) float float4x;   // MFMA 16x16 C/D frag
typedef unsigned short u16;
typedef unsigned int u32;

__device__ __forceinline__ float bf2f(u16 u) {
    return __uint_as_float(((u32)u) << 16);
}
__device__ __forceinline__ u16 f2bf(float f) {
    u32 u = __float_as_uint(f);
    u32 r = (u + 0x7fffu + ((u >> 16) & 1u)) >> 16;   // round-to-nearest-even
    return (u16)r;
}
// monotone float<->u32 mapping (u-order == f-order), exact; for atomicMax on floats
__device__ __forceinline__ u32 fenc(float f) {
    u32 b = __float_as_uint(f);
    return b ^ (0x80000000u | (u32)((int)b >> 31));
}
__device__ __forceinline__ float fdec(u32 u) {
    u32 b = (u & 0x80000000u) ? (u ^ 0x80000000u) : ~u;
    return __uint_as_float(b);
}
// fast sigmoid (v_exp_f32 path); error ~2ulp, rounded to bf16 downstream anyway
__device__ __forceinline__ float fsig(float v) {
    return __builtin_amdgcn_rcpf(1.f + __expf(-v));
}
// fast exact-GELU: Abramowitz-Stegun 7.1.26 erf, max abs err 1.5e-7 (<< bf16 ulp).
__device__ __forceinline__ float fgelu(float v) {
    const float is2 = 0.70710678118654752f;
    float z = v * is2;
    float ax = fabsf(z);
    float t = __builtin_amdgcn_rcpf(1.f + 0.3275911f * ax);
    float p = ((((1.061405429f * t - 1.453152027f) * t) + 1.421413741f) * t - 0.284496736f) * t
              + 0.254829592f;
    float e = 1.f - p * t * __expf(-ax * ax);        // erf(|z|)
    float er = copysignf(e, z);
    return 0.5f * v * (1.f + er);
}

// ---------------------------------------------------------------- sizes
// B=4, H=W=96, C_in=64, C_hid=256, C_out=64, padded HP=98. c split: 8 groups x 32.
// 5-dispatch pipeline: gl1(+border+gl2init) -> gate1 -> gemm1 -> gate2 -> conv2.
// BUDGET LEDGER (all measured):
//   r14: gemm1+conv2 ~= 34.5 us (conv2 ~25, MfmaUtil 18%, MFMA floor ~1.3)
//   r16: gl1+gate1+gate2 ~= 5.1 us;  r12: dispatch boundary <= 2 us each
//   fixed remainder ~= 90 us ~= 2 x 45-us 256-MiB harness poison fills (in timed
//   replay, NOT kernel-addressable). Achievable frontier ~= 90 + kernels.
// conv2 attempt history (ALL neutral): r10 wave-split (regressed), r15 occupancy
// 3blk/CU + gl_lds + conflict-free swizzle, r17 4-phase (2 g-planes/phase).
// ROUND-18: catalog lesson #7 (L2-fit data -> staging is pure overhead; attn
// m168->m169 +26%): conv2 B-reads measured 93% L2-hit (FETCH 4.2MB vs 59MB
// logical). DELETE the LDS tier: read B-frags direct from global/L2. Zero
// cross-thread data -> ZERO barriers -> waves fully self-paced; B loads are
// 1KB coalesced per wave (16px x 4quads contiguous, 64B-aligned). Same acc
// order (g outer, k, nt) -> bitwise-identical output.
// PRE-COMMIT: if total >= 130.5 us, declare harness-dominated plateau.
// NOTE (round-5): border-zero/gl2-init must precede gemm1 via dispatch boundary.
// NOTE (round-11 FAILED): never hand-roll cross-block sync (XCD L2 non-coherence).
// ws layout (bytes):
//   h2p   @ 4718592   : 4*8*98*98*32*2= 19,668,992 bf16 [b][g][98][98][32]
//   W1A   @ 24387584  : 4*256*64*2    = 131,072    bf16 [b][oc][c64]
//   W2A   @ 24518656  : 4*8*9*64*32*2 = 1,179,648  bf16 [b][g][k][oc][c32]
//   gl1   @ 25698304  : 4*64*4       = 1,024      fp32 per-(b,c) global max
//   gl2   @ 25796608  : 4*9*256*4    = 36,864     u32 fenc(max) [b][k=ki*3+kj][c]

// blocks 0..255: global max per (b,c); blocks 256..287: h2p border zero + gl2 init
__global__ __launch_bounds__(256) void k_gl1(const float* __restrict__ x, float* __restrict__ gl1,
                                             u32* __restrict__ h2p32, u32* __restrict__ gl2u) {
    if (blockIdx.x >= 256) {                        // border-zero duty (plane bi)
        int t = threadIdx.x;
        int plane_id = blockIdx.x - 256;
        u32* plane = h2p32 + plane_id * (98 * 98 * 16);
        for (int i = t; i < 1568; i += 256) plane[i] = 0u;                  // row 0
        for (int i = t; i < 1568; i += 256) plane[97 * 98 * 16 + i] = 0u;   // row 97
        for (int i = t; i < 3072; i += 256) {                               // cols 0 & 97
            int r = (i >> 5) + 1;
            int p = ((i >> 4) & 1) * 97;
            int w = i & 15;
            plane[(r * 98 + p) * 16 + w] = 0u;
        }
        // gl2 init to u32 0 (== most-negative in fenc order); 9216 u32 over 32 blocks
        for (int i = plane_id * 288 + t; i < (plane_id + 1) * 288; i += 256)
            gl2u[i] = 0u;
        return;
    }
    int b = blockIdx.x >> 6, c = blockIdx.x & 63;
    const float4* p = (const float4*)(x + (b * 64 + c) * 9216);
    float m = -1e30f;
    #pragma unroll
    for (int i = 0; i < 9; i++) {
        float4 v = p[i * 256 + threadIdx.x];
        m = fmaxf(m, fmaxf(fmaxf(v.x, v.y), fmaxf(v.z, v.w)));
    }
    __shared__ float red[256];
    red[threadIdx.x] = m;
    __syncthreads();
    for (int s = 128; s > 0; s >>= 1) {
        if (threadIdx.x < s) red[threadIdx.x] = fmaxf(red[threadIdx.x], red[threadIdx.x + s]);
        __syncthreads();
    }
    if (threadIdx.x == 0) gl1[b * 64 + c] = red[0];
}

// fc1 gating -> W1A[b][oc=256][c=64]; 64 blocks = (b, slice16)
__global__ __launch_bounds__(256) void k_gate1(const float* __restrict__ gl1,
                                               const float* __restrict__ ce, const float* __restrict__ gd,
                                               const float* __restrict__ gd2, const float* __restrict__ ci,
                                               const float* __restrict__ w1, u16* __restrict__ W1A) {
    int b = blockIdx.x >> 4, s = blockIdx.x & 15;
    int t = threadIdx.x;
    __shared__ float rce[64], out1[64], ocp[256];
    float cew = ce[0], gdw = gd[0], gd2w = gd2[0];
    if (t < 64) {
        float r = fmaxf(gl1[b * 64 + t] * cew, 0.f);
        rce[t] = r;
        out1[t] = r * gdw;
    }
    __syncthreads();
    {
        int p = t >> 5, oi = t & 31;
        float sv = 0.f;
        #pragma unroll
        for (int g = 0; g < 8; g++) sv += rce[p * 8 + g] * ci[oi * 8 + g];
        ocp[t] = fmaxf(sv, 0.f) * gd2w;
    }
    __syncthreads();
    u16* Wb = W1A + b * 256 * 64;
    #pragma unroll
    for (int i = 0; i < 4; i++) {
        int idx = s * 1024 + i * 256 + t;
        int o = idx >> 6, c = idx & 63;
        float v = out1[c] + ocp[o];
        Wb[idx] = f2bf(fsig(v) * w1[idx]);
    }
}

// h2p interior = gelu( W1A[b] (256x64) @ x-slab (64 x 48px) ); half-row per block.
// Fused: x load+transpose via LDS slab; 3x3-pool maxes via butterfly + atomicMax(fenc).
__global__ __launch_bounds__(256) void k_gemm1(const u16* __restrict__ W1A, const float* __restrict__ x,
                                               u16* __restrict__ h2p, u32* __restrict__ gl2u) {
    int bi = blockIdx.x;
    int b = bi / 192, rem = bi % 192;
    int y = rem >> 1, half = rem & 1;
    int t = threadIdx.x, wave = t >> 6, lane = t & 63, l15 = lane & 15, quad = lane >> 4;

    __shared__ __align__(16) u16 xs[48 * 72];       // [px][c], row pad 72 (144 B, 16B-mult)
    const float* xb = x + (b * 64) * 9216 + y * 96 + half * 48;
    const float2* xb2 = (const float2*)xb;          // 8B-aligned (all offsets even floats)
    #pragma unroll
    for (int i = 0; i < 6; i++) {
        int idx = i * 256 + t;                      // 1536 = 64c x 24 px-pairs
        int c = idx / 24, px2 = idx - c * 24;
        float2 v = xb2[c * 4608 + px2];
        int px = px2 * 2;
        xs[px * 72 + c] = f2bf(v.x);
        xs[(px + 1) * 72 + c] = f2bf(v.y);
    }
    __syncthreads();

    float4x acc[4][3];
    #pragma unroll
    for (int mt = 0; mt < 4; mt++)
        #pragma unroll
        for (int nt = 0; nt < 3; nt++) acc[mt][nt] = (float4x){0.f, 0.f, 0.f, 0.f};
    const u16* Wb = W1A + b * 256 * 64;
    #pragma unroll
    for (int c0 = 0; c0 < 64; c0 += 32) {
        short8x bfr[3];
        #pragma unroll
        for (int nt = 0; nt < 3; nt++)
            bfr[nt] = *(const short8x*)(xs + (nt * 16 + l15) * 72 + c0 + quad * 8);
        #pragma unroll
        for (int mt = 0; mt < 4; mt++) {
            int oc = wave * 64 + mt * 16 + l15;
            short8x afr = *(const short8x*)(Wb + oc * 64 + c0 + quad * 8);
            #pragma unroll
            for (int nt = 0; nt < 3; nt++)
                acc[mt][nt] = __builtin_amdgcn_mfma_f32_16x16x32_bf16(afr, bfr[nt], acc[mt][nt], 0, 0, 0);
        }
    }
    float gf[4][3][4];
    #pragma unroll
    for (int mt = 0; mt < 4; mt++) {
        #pragma unroll
        for (int nt = 0; nt < 3; nt++) {
            int xx = half * 48 + nt * 16 + l15;
            int oc0 = wave * 64 + mt * 16 + quad * 4;
            int g = oc0 >> 5, cl = oc0 & 31;
            u16 pk[4];
            #pragma unroll
            for (int r = 0; r < 4; r++) {
                float gl = fgelu(acc[mt][nt][r]);   // exact-GELU via A-S erf (1.5e-7)
                gf[mt][nt][r] = gl;
                pk[r] = f2bf(gl);
            }
            u16* dst = h2p + ((((b * 8 + g) * 98 + y + 1) * 98) + xx + 1) * 32 + cl;
            *(ushort4*)dst = make_ushort4(pk[0], pk[1], pk[2], pk[3]);
        }
    }
    // 3x3-pool partial maxes: butterfly over 16 px lanes, then atomicMax(fenc)
    int ki = y >> 5;
    int kA = ki * 3 + (half == 0 ? 0 : 1);
    int kB = ki * 3 + (half == 0 ? 1 : 2);
    #pragma unroll
    for (int mt = 0; mt < 4; mt++) {
        float vA[4], vB[4];
        #pragma unroll
        for (int r = 0; r < 4; r++) {
            if (half == 0) { vA[r] = fmaxf(gf[mt][0][r], gf[mt][1][r]); vB[r] = gf[mt][2][r]; }
            else           { vA[r] = gf[mt][0][r]; vB[r] = fmaxf(gf[mt][1][r], gf[mt][2][r]); }
        }
        #pragma unroll
        for (int m = 1; m < 16; m <<= 1) {
            #pragma unroll
            for (int r = 0; r < 4; r++) {
                vA[r] = fmaxf(vA[r], __shfl_xor(vA[r], m));
                vB[r] = fmaxf(vB[r], __shfl_xor(vB[r], m));
            }
        }
        if (l15 == 0) {
            #pragma unroll
            for (int r = 0; r < 4; r++) {
                int oc = wave * 64 + mt * 16 + quad * 4 + r;
                atomicMax(&gl2u[(b * 9 + kA) * 256 + oc], fenc(vA[r]));
                atomicMax(&gl2u[(b * 9 + kB) * 256 + oc], fenc(vB[r]));
            }
        }
    }
}

// Fused fc2 gating: each of 64 blocks (b,slice) decodes gl2, computes out2/ocp2
// (redundantly per block), writes its W2A slice.
__global__ __launch_bounds__(256) void k_gate2(const u32* __restrict__ gl2u,
                                               const float* __restrict__ ce, const float* __restrict__ gd,
                                               const float* __restrict__ gd2, const float* __restrict__ ci,
                                               const float* __restrict__ w2, u16* __restrict__ W2A) {
    int b = blockIdx.x >> 4, s = blockIdx.x & 15;
    int t = threadIdx.x;
    __shared__ float rce[256][5];
    __shared__ float out2[256][9];
    __shared__ float ocp2[64][9];
    {
        float gl[9];
        #pragma unroll
        for (int k = 0; k < 9; k++) gl[k] = fdec(gl2u[(b * 9 + k) * 256 + t]);
        float r[5];
        #pragma unroll
        for (int n = 0; n < 5; n++) {
            float sv = 0.f;
            #pragma unroll
            for (int k = 0; k < 9; k++) sv += gl[k] * ce[n * 9 + k];
            r[n] = fmaxf(sv, 0.f);
            rce[t][n] = r[n];
        }
        #pragma unroll
        for (int k = 0; k < 9; k++) {
            float sv = 0.f;
            #pragma unroll
            for (int n = 0; n < 5; n++) sv += r[n] * gd[k * 5 + n];
            out2[t][k] = sv;
        }
    }
    __syncthreads();
    if (t < 64) {
        int p = t >> 1, oi = t & 1;
        float rt[5];
        #pragma unroll
        for (int n = 0; n < 5; n++) {
            float sv = 0.f;
            #pragma unroll
            for (int g = 0; g < 8; g++) sv += rce[p * 8 + g][n] * ci[oi * 8 + g];
            rt[n] = fmaxf(sv, 0.f);
        }
        #pragma unroll
        for (int k = 0; k < 9; k++) {
            float sv = 0.f;
            #pragma unroll
            for (int n = 0; n < 5; n++) sv += rt[n] * gd2[k * 5 + n];
            ocp2[t][k] = sv;
        }
    }
    __syncthreads();
    u16* Wb = W2A + b * (8 * 9 * 64 * 32);
    for (int it = 0; it < 36; it++) {
        int flat = s * 9216 + it * 256 + t;
        int cl = flat & 31;
        int o = (flat >> 5) & 63;
        int rest = flat >> 11;           // = g*9 + k
        int k = rest % 9, g = rest / 9;
        int c = g * 32 + cl;
        float v = out2[c][k] + ocp2[o][k];
        Wb[flat] = f2bf(fsig(v) * w2[(o * 256 + c) * 9 + k]);
    }
}

// out[b][oc][y][x] = sum_{g,k,cl} W2A[b][g][k][oc][cl] * h2p[b][g][y+i][x+j][cl]
// ROUND-18: BARRIER-FREE conv2. No LDS, no __syncthreads — B-frags read directly
// from global (93% L2-hit measured). Each B load is a coalesced 1KB wave-load
// (16 px x 4 quads contiguous, 64B-aligned). Waves fully independent; compiler
// pipelines the 36 loads/g against the 27 MFMAs via vmcnt. 768 blocks x 256 thr,
// __launch_bounds__(256,3). acc order (g outer, k, nt) -> bitwise-identical.
__global__ __launch_bounds__(256, 3) void k_conv2(const u16* __restrict__ W2A, const u16* __restrict__ h2p,
                                                  float* __restrict__ out) {
    int bi = blockIdx.x;
    int b = bi / 192, rem = bi % 192;
    int y = rem >> 1, half = rem & 1;
    int t = threadIdx.x, wave = t >> 6, lane = t & 63, l15 = lane & 15, quad = lane >> 4;

    const int plane_sz = 98 * 98 * 32;
    // per-lane B base (u16 units) within a plane, for row ki=0, nt=0, kj=0:
    // ((y + ki)*98 + half*48 + nt*16 + l15 + kj)*32 + quad*8
    int bbase = (y * 98 + half * 48 + l15) * 32 + quad * 8;
    int abase = (wave * 16 + l15) * 32 + quad * 8;

    float4x acc[3];
    #pragma unroll
    for (int nt = 0; nt < 3; nt++) acc[nt] = (float4x){0.f, 0.f, 0.f, 0.f};

    #pragma unroll 1
    for (int g = 0; g < 8; g++) {
        const u16* Wg = W2A + (b * 8 + g) * (9 * 64 * 32);
        const u16* Pg = h2p + (b * 8 + g) * plane_sz;
        #pragma unroll
        for (int k = 0; k < 9; k++) {
            int ki = k / 3, kj = k - ki * 3;
            // A-frag: one coalesced 1024B wave-load from L2-resident W2A
            short8x af = *(const short8x*)(Wg + k * (64 * 32) + abase);
            #pragma unroll
            for (int nt = 0; nt < 3; nt++) {
                short8x bf = *(const short8x*)(Pg + bbase + (ki * 98 + nt * 16 + kj) * 32);
                acc[nt] = __builtin_amdgcn_mfma_f32_16x16x32_bf16(af, bf, acc[nt], 0, 0, 0);
            }
        }
    }
    #pragma unroll
    for (int nt = 0; nt < 3; nt++) {
        int xx = half * 48 + nt * 16 + l15;
        #pragma unroll
        for (int r = 0; r < 4; r++) {
            int oc = wave * 16 + quad * 4 + r;
            out[((b * 64 + oc) * 96 + y) * 96 + xx] = acc[nt][r];
        }
    }
}

extern "C" void kernel_launch(void* const* d_in, const int* in_sizes, int n_in,
                              void* d_out, int out_size, void* d_ws, size_t ws_size,
                              hipStream_t stream) {
    const float* x    = (const float*)d_in[0];
    const float* w1   = (const float*)d_in[1];
    const float* ce1  = (const float*)d_in[2];
    const float* gd1  = (const float*)d_in[3];
    const float* gd21 = (const float*)d_in[4];
    const float* ci1  = (const float*)d_in[5];
    const float* w2   = (const float*)d_in[6];
    const float* ce2  = (const float*)d_in[7];
    const float* gd2  = (const float*)d_in[8];
    const float* gd22 = (const float*)d_in[9];
    const float* ci2  = (const float*)d_in[10];
    float* out = (float*)d_out;

    char* ws = (char*)d_ws;
    u16*   h2p  = (u16*)(ws + 4718592);
    u16*   W1A  = (u16*)(ws + 24387584);
    u16*   W2A  = (u16*)(ws + 24518656);
    float* gl1  = (float*)(ws + 25698304);
    u32*   gl2u = (u32*)(ws + 25796608);

    k_gl1  <<<288, 256, 0, stream>>>(x, gl1, (u32*)h2p, gl2u);
    k_gate1<<<64,  256, 0, stream>>>(gl1, ce1, gd1, gd21, ci1, w1, W1A);
    k_gemm1<<<768, 256, 0, stream>>>(W1A, x, h2p, gl2u);
    k_gate2<<<64,  256, 0, stream>>>(gl2u, ce2, gd2, gd22, ci2, w2, W2A);
    k_conv2<<<768, 256, 0, stream>>>(W2A, h2p, out);
}

// Round 11
// 131.648 us; speedup vs baseline: 1.2292x; 1.2292x over previous
//
#include <hip/hip_runtime.h>
#include <math.h>

typedef __attribute__((ext_vector_type(8))) short short8x;   // 8 x bf16 = 4 VGPRs
typedef __attribute__((ext_vector_type(4))) float float4x;   // MFMA 16x16 C/D frag
typedef unsigned short u16;
typedef unsigned int u32;

__device__ __forceinline__ float bf2f(u16 u) {
    return __uint_as_float(((u32)u) << 16);
}
__device__ __forceinline__ u16 f2bf(float f) {
    u32 u = __float_as_uint(f);
    u32 r = (u + 0x7fffu + ((u >> 16) & 1u)) >> 16;   // round-to-nearest-even
    return (u16)r;
}
// monotone float<->u32 mapping (u-order == f-order), exact; for atomicMax on floats
__device__ __forceinline__ u32 fenc(float f) {
    u32 b = __float_as_uint(f);
    return b ^ (0x80000000u | (u32)((int)b >> 31));
}
__device__ __forceinline__ float fdec(u32 u) {
    u32 b = (u & 0x80000000u) ? (u ^ 0x80000000u) : ~u;
    return __uint_as_float(b);
}
// fast sigmoid (v_exp_f32 path); error ~2ulp, rounded to bf16 downstream anyway
__device__ __forceinline__ float fsig(float v) {
    return __builtin_amdgcn_rcpf(1.f + __expf(-v));
}
// fast exact-GELU: Abramowitz-Stegun 7.1.26 erf, max abs err 1.5e-7 (<< bf16 ulp).
__device__ __forceinline__ float fgelu(float v) {
    const float is2 = 0.70710678118654752f;
    float z = v * is2;
    float ax = fabsf(z);
    float t = __builtin_amdgcn_rcpf(1.f + 0.3275911f * ax);
    float p = ((((1.061405429f * t - 1.453152027f) * t) + 1.421413741f) * t - 0.284496736f) * t
              + 0.254829592f;
    float e = 1.f - p * t * __expf(-ax * ax);        // erf(|z|)
    float er = copysignf(e, z);
    return 0.5f * v * (1.f + er);
}

// ---------------------------------------------------------------- sizes
// B=4, H=W=96, C_in=64, C_hid=256, C_out=64, padded HP=98. c split: 8 groups x 32.
// 5-dispatch pipeline (MEASURED BEST, 131.99 us):
//   gl1(+border+gl2init) -> gate1 -> gemm1 -> gate2 -> conv2
// FINAL BUDGET LEDGER (all measured, cross-validated):
//   conv2 ~= 24.5 us  (r14 REP=8: 199/8; r18 subtraction: 54.3-29.8 — agree)
//   gemm1 ~= 9.6 us;  gl1+gate1+gate2 ~= 5.1 us (r16);  boundaries <= 2 us each
//   fixed ~= 90 us = 2 x 45-us 256-MiB harness poison fills inside the timed
//   replay (WRITE_SIZE=262144 KB rows in every top-5) — NOT kernel-addressable.
// conv2 structural variants ALL failed to beat 24.5 us:
//   r10 wave-split (137.0), r15 3blk/CU+gl_lds+conflict-free swizzle (132.1),
//   r17 4-phase (133.4), r18 barrier-free direct-L2 (161.8: VGPR=32, no load
//   pipelining -> serial L2 latency; staging tier is NECESSARY here).
// NOTE (round-5): border-zero/gl2-init must precede gemm1 via dispatch boundary.
// NOTE (round-11 FAILED): never hand-roll cross-block sync (XCD L2 non-coherence);
// cross-block data must cross a dispatch boundary.
// ws layout (bytes):
//   h2p   @ 4718592   : 4*8*98*98*32*2= 19,668,992 bf16 [b][g][98][98][32]
//   W1A   @ 24387584  : 4*256*64*2    = 131,072    bf16 [b][oc][c64]
//   W2A   @ 24518656  : 4*8*9*64*32*2 = 1,179,648  bf16 [b][g][k][oc][c32]
//   gl1   @ 25698304  : 4*64*4       = 1,024      fp32 per-(b,c) global max
//   gl2   @ 25796608  : 4*9*256*4    = 36,864     u32 fenc(max) [b][k=ki*3+kj][c]

// blocks 0..255: global max per (b,c); blocks 256..287: h2p border zero + gl2 init
__global__ __launch_bounds__(256) void k_gl1(const float* __restrict__ x, float* __restrict__ gl1,
                                             u32* __restrict__ h2p32, u32* __restrict__ gl2u) {
    if (blockIdx.x >= 256) {                        // border-zero duty (plane bi)
        int t = threadIdx.x;
        int plane_id = blockIdx.x - 256;
        u32* plane = h2p32 + plane_id * (98 * 98 * 16);
        for (int i = t; i < 1568; i += 256) plane[i] = 0u;                  // row 0
        for (int i = t; i < 1568; i += 256) plane[97 * 98 * 16 + i] = 0u;   // row 97
        for (int i = t; i < 3072; i += 256) {                               // cols 0 & 97
            int r = (i >> 5) + 1;
            int p = ((i >> 4) & 1) * 97;
            int w = i & 15;
            plane[(r * 98 + p) * 16 + w] = 0u;
        }
        // gl2 init to u32 0 (== most-negative in fenc order); 9216 u32 over 32 blocks
        for (int i = plane_id * 288 + t; i < (plane_id + 1) * 288; i += 256)
            gl2u[i] = 0u;
        return;
    }
    int b = blockIdx.x >> 6, c = blockIdx.x & 63;
    const float4* p = (const float4*)(x + (b * 64 + c) * 9216);
    float m = -1e30f;
    #pragma unroll
    for (int i = 0; i < 9; i++) {
        float4 v = p[i * 256 + threadIdx.x];
        m = fmaxf(m, fmaxf(fmaxf(v.x, v.y), fmaxf(v.z, v.w)));
    }
    __shared__ float red[256];
    red[threadIdx.x] = m;
    __syncthreads();
    for (int s = 128; s > 0; s >>= 1) {
        if (threadIdx.x < s) red[threadIdx.x] = fmaxf(red[threadIdx.x], red[threadIdx.x + s]);
        __syncthreads();
    }
    if (threadIdx.x == 0) gl1[b * 64 + c] = red[0];
}

// fc1 gating -> W1A[b][oc=256][c=64]; 64 blocks = (b, slice16)
__global__ __launch_bounds__(256) void k_gate1(const float* __restrict__ gl1,
                                               const float* __restrict__ ce, const float* __restrict__ gd,
                                               const float* __restrict__ gd2, const float* __restrict__ ci,
                                               const float* __restrict__ w1, u16* __restrict__ W1A) {
    int b = blockIdx.x >> 4, s = blockIdx.x & 15;
    int t = threadIdx.x;
    __shared__ float rce[64], out1[64], ocp[256];
    float cew = ce[0], gdw = gd[0], gd2w = gd2[0];
    if (t < 64) {
        float r = fmaxf(gl1[b * 64 + t] * cew, 0.f);
        rce[t] = r;
        out1[t] = r * gdw;
    }
    __syncthreads();
    {
        int p = t >> 5, oi = t & 31;
        float sv = 0.f;
        #pragma unroll
        for (int g = 0; g < 8; g++) sv += rce[p * 8 + g] * ci[oi * 8 + g];
        ocp[t] = fmaxf(sv, 0.f) * gd2w;
    }
    __syncthreads();
    u16* Wb = W1A + b * 256 * 64;
    #pragma unroll
    for (int i = 0; i < 4; i++) {
        int idx = s * 1024 + i * 256 + t;
        int o = idx >> 6, c = idx & 63;
        float v = out1[c] + ocp[o];
        Wb[idx] = f2bf(fsig(v) * w1[idx]);
    }
}

// h2p interior = gelu( W1A[b] (256x64) @ x-slab (64 x 48px) ); half-row per block.
// Fused: x load+transpose via LDS slab; 3x3-pool maxes via butterfly + atomicMax(fenc).
__global__ __launch_bounds__(256) void k_gemm1(const u16* __restrict__ W1A, const float* __restrict__ x,
                                               u16* __restrict__ h2p, u32* __restrict__ gl2u) {
    int bi = blockIdx.x;
    int b = bi / 192, rem = bi % 192;
    int y = rem >> 1, half = rem & 1;
    int t = threadIdx.x, wave = t >> 6, lane = t & 63, l15 = lane & 15, quad = lane >> 4;

    __shared__ __align__(16) u16 xs[48 * 72];       // [px][c], row pad 72 (144 B, 16B-mult)
    const float* xb = x + (b * 64) * 9216 + y * 96 + half * 48;
    const float2* xb2 = (const float2*)xb;          // 8B-aligned (all offsets even floats)
    #pragma unroll
    for (int i = 0; i < 6; i++) {
        int idx = i * 256 + t;                      // 1536 = 64c x 24 px-pairs
        int c = idx / 24, px2 = idx - c * 24;
        float2 v = xb2[c * 4608 + px2];
        int px = px2 * 2;
        xs[px * 72 + c] = f2bf(v.x);
        xs[(px + 1) * 72 + c] = f2bf(v.y);
    }
    __syncthreads();

    float4x acc[4][3];
    #pragma unroll
    for (int mt = 0; mt < 4; mt++)
        #pragma unroll
        for (int nt = 0; nt < 3; nt++) acc[mt][nt] = (float4x){0.f, 0.f, 0.f, 0.f};
    const u16* Wb = W1A + b * 256 * 64;
    #pragma unroll
    for (int c0 = 0; c0 < 64; c0 += 32) {
        short8x bfr[3];
        #pragma unroll
        for (int nt = 0; nt < 3; nt++)
            bfr[nt] = *(const short8x*)(xs + (nt * 16 + l15) * 72 + c0 + quad * 8);
        #pragma unroll
        for (int mt = 0; mt < 4; mt++) {
            int oc = wave * 64 + mt * 16 + l15;
            short8x afr = *(const short8x*)(Wb + oc * 64 + c0 + quad * 8);
            #pragma unroll
            for (int nt = 0; nt < 3; nt++)
                acc[mt][nt] = __builtin_amdgcn_mfma_f32_16x16x32_bf16(afr, bfr[nt], acc[mt][nt], 0, 0, 0);
        }
    }
    float gf[4][3][4];
    #pragma unroll
    for (int mt = 0; mt < 4; mt++) {
        #pragma unroll
        for (int nt = 0; nt < 3; nt++) {
            int xx = half * 48 + nt * 16 + l15;
            int oc0 = wave * 64 + mt * 16 + quad * 4;
            int g = oc0 >> 5, cl = oc0 & 31;
            u16 pk[4];
            #pragma unroll
            for (int r = 0; r < 4; r++) {
                float gl = fgelu(acc[mt][nt][r]);   // exact-GELU via A-S erf (1.5e-7)
                gf[mt][nt][r] = gl;
                pk[r] = f2bf(gl);
            }
            u16* dst = h2p + ((((b * 8 + g) * 98 + y + 1) * 98) + xx + 1) * 32 + cl;
            *(ushort4*)dst = make_ushort4(pk[0], pk[1], pk[2], pk[3]);
        }
    }
    // 3x3-pool partial maxes: butterfly over 16 px lanes, then atomicMax(fenc)
    int ki = y >> 5;
    int kA = ki * 3 + (half == 0 ? 0 : 1);
    int kB = ki * 3 + (half == 0 ? 1 : 2);
    #pragma unroll
    for (int mt = 0; mt < 4; mt++) {
        float vA[4], vB[4];
        #pragma unroll
        for (int r = 0; r < 4; r++) {
            if (half == 0) { vA[r] = fmaxf(gf[mt][0][r], gf[mt][1][r]); vB[r] = gf[mt][2][r]; }
            else           { vA[r] = gf[mt][0][r]; vB[r] = fmaxf(gf[mt][1][r], gf[mt][2][r]); }
        }
        #pragma unroll
        for (int m = 1; m < 16; m <<= 1) {
            #pragma unroll
            for (int r = 0; r < 4; r++) {
                vA[r] = fmaxf(vA[r], __shfl_xor(vA[r], m));
                vB[r] = fmaxf(vB[r], __shfl_xor(vB[r], m));
            }
        }
        if (l15 == 0) {
            #pragma unroll
            for (int r = 0; r < 4; r++) {
                int oc = wave * 64 + mt * 16 + quad * 4 + r;
                atomicMax(&gl2u[(b * 9 + kA) * 256 + oc], fenc(vA[r]));
                atomicMax(&gl2u[(b * 9 + kB) * 256 + oc], fenc(vB[r]));
            }
        }
    }
}

// Fused fc2 gating: each of 64 blocks (b,slice) decodes gl2, computes out2/ocp2
// (redundantly per block), writes its W2A slice.
__global__ __launch_bounds__(256) void k_gate2(const u32* __restrict__ gl2u,
                                               const float* __restrict__ ce, const float* __restrict__ gd,
                                               const float* __restrict__ gd2, const float* __restrict__ ci,
                                               const float* __restrict__ w2, u16* __restrict__ W2A) {
    int b = blockIdx.x >> 4, s = blockIdx.x & 15;
    int t = threadIdx.x;
    __shared__ float rce[256][5];
    __shared__ float out2[256][9];
    __shared__ float ocp2[64][9];
    {
        float gl[9];
        #pragma unroll
        for (int k = 0; k < 9; k++) gl[k] = fdec(gl2u[(b * 9 + k) * 256 + t]);
        float r[5];
        #pragma unroll
        for (int n = 0; n < 5; n++) {
            float sv = 0.f;
            #pragma unroll
            for (int k = 0; k < 9; k++) sv += gl[k] * ce[n * 9 + k];
            r[n] = fmaxf(sv, 0.f);
            rce[t][n] = r[n];
        }
        #pragma unroll
        for (int k = 0; k < 9; k++) {
            float sv = 0.f;
            #pragma unroll
            for (int n = 0; n < 5; n++) sv += r[n] * gd[k * 5 + n];
            out2[t][k] = sv;
        }
    }
    __syncthreads();
    if (t < 64) {
        int p = t >> 1, oi = t & 1;
        float rt[5];
        #pragma unroll
        for (int n = 0; n < 5; n++) {
            float sv = 0.f;
            #pragma unroll
            for (int g = 0; g < 8; g++) sv += rce[p * 8 + g][n] * ci[oi * 8 + g];
            rt[n] = fmaxf(sv, 0.f);
        }
        #pragma unroll
        for (int k = 0; k < 9; k++) {
            float sv = 0.f;
            #pragma unroll
            for (int n = 0; n < 5; n++) sv += rt[n] * gd2[k * 5 + n];
            ocp2[t][k] = sv;
        }
    }
    __syncthreads();
    u16* Wb = W2A + b * (8 * 9 * 64 * 32);
    for (int it = 0; it < 36; it++) {
        int flat = s * 9216 + it * 256 + t;
        int cl = flat & 31;
        int o = (flat >> 5) & 63;
        int rest = flat >> 11;           // = g*9 + k
        int k = rest % 9, g = rest / 9;
        int c = g * 32 + cl;
        float v = out2[c][k] + ocp2[o][k];
        Wb[flat] = f2bf(fsig(v) * w2[(o * 256 + c) * 9 + k]);
    }
}

// out[b][oc][y][x] = sum_{g,k,cl} W2A[b][g][k][oc][cl] * h2p[b][g][y+i][x+j][cl]
// Block = (b, y, px-half): 768 blocks x 256 thr (12 waves/CU). B halo slab in LDS
// (3 rows x 50 px x 32c = 9.6 KB), DOUBLE-BUFFERED with register prefetch: g+1's
// slab global-loads issue before compute(g); their vmcnt-wait lands after the
// 27-MFMA burst -> global latency overlapped. One barrier per g-iter.
// A-frags stream from L2-resident W2A (coalesced 1024B wave-loads).
// acc order (g outer, k inner) unchanged -> bitwise-identical output.
__global__ __launch_bounds__(256) void k_conv2(const u16* __restrict__ W2A, const u16* __restrict__ h2p,
                                               float* __restrict__ out) {
    int bi = blockIdx.x;
    int b = bi / 192, rem = bi % 192;
    int y = rem >> 1, half = rem & 1;
    int t = threadIdx.x, wave = t >> 6, lane = t & 63, l15 = lane & 15, quad = lane >> 4;
    __shared__ __align__(16) u16 Bls[2][3 * 50 * 32];   // 2 x 9,600 B  [i][px_local 50][cl]

    // per-thread staging offsets (600 uint4 = 256+256+88; slot 2 valid iff t<88)
    int offs[3];
    #pragma unroll
    for (int j = 0; j < 3; j++) {
        int i = t + j * 256;
        int r = i / 200, c16 = i - r * 200;
        offs[j] = ((y + r) * 98 + half * 48) * 32 + c16 * 8;   // u16 units
    }
    const int plane_sz = 98 * 98 * 32;
    uint4 p0, p1, p2;
    {   // prologue: stage g=0
        const u16* pl = h2p + (b * 8) * plane_sz;
        p0 = *(const uint4*)(pl + offs[0]);
        p1 = *(const uint4*)(pl + offs[1]);
        if (t < 88) p2 = *(const uint4*)(pl + offs[2]);
        uint4* Bd = (uint4*)Bls[0];
        Bd[t] = p0;
        Bd[t + 256] = p1;
        if (t < 88) Bd[t + 512] = p2;
    }

    float4x acc[3];
    #pragma unroll
    for (int nt = 0; nt < 3; nt++) acc[nt] = (float4x){0.f, 0.f, 0.f, 0.f};

    for (int g = 0; g < 8; g++) {
        __syncthreads();                 // buf[g&1] ready for all waves
        if (g < 7) {                     // issue g+1 prefetch (async; waited at write below)
            const u16* pl = h2p + (b * 8 + g + 1) * plane_sz;
            p0 = *(const uint4*)(pl + offs[0]);
            p1 = *(const uint4*)(pl + offs[1]);
            if (t < 88) p2 = *(const uint4*)(pl + offs[2]);
        }
        const u16* Wg = W2A + (b * 8 + g) * (9 * 64 * 32);
        const u16* Bcur = Bls[g & 1];
        #pragma unroll
        for (int k = 0; k < 9; k++) {
            int ki = k / 3, kj = k - ki * 3;
            // A-frag: oc rows [wave*16, +16), one coalesced 1024B global load per wave
            short8x af = *(const short8x*)(Wg + (k * 64 + wave * 16 + l15) * 32 + quad * 8);
            #pragma unroll
            for (int nt = 0; nt < 3; nt++) {
                int pxl = nt * 16 + l15 + kj;      // local px in [0,50)
                short8x bf = *(const short8x*)(Bcur + (ki * 50 + pxl) * 32 + quad * 8);
                acc[nt] = __builtin_amdgcn_mfma_f32_16x16x32_bf16(af, bf, acc[nt], 0, 0, 0);
            }
        }
        if (g < 7) {                     // write prefetched slab to the other buffer
            uint4* Bd = (uint4*)Bls[(g + 1) & 1];
            Bd[t] = p0;
            Bd[t + 256] = p1;
            if (t < 88) Bd[t + 512] = p2;
        }
    }
    #pragma unroll
    for (int nt = 0; nt < 3; nt++) {
        int xx = half * 48 + nt * 16 + l15;
        #pragma unroll
        for (int r = 0; r < 4; r++) {
            int oc = wave * 16 + quad * 4 + r;
            out[((b * 64 + oc) * 96 + y) * 96 + xx] = acc[nt][r];
        }
    }
}

extern "C" void kernel_launch(void* const* d_in, const int* in_sizes, int n_in,
                              void* d_out, int out_size, void* d_ws, size_t ws_size,
                              hipStream_t stream) {
    const float* x    = (const float*)d_in[0];
    const float* w1   = (const float*)d_in[1];
    const float* ce1  = (const float*)d_in[2];
    const float* gd1  = (const float*)d_in[3];
    const float* gd21 = (const float*)d_in[4];
    const float* ci1  = (const float*)d_in[5];
    const float* w2   = (const float*)d_in[6];
    const float* ce2  = (const float*)d_in[7];
    const float* gd2  = (const float*)d_in[8];
    const float* gd22 = (const float*)d_in[9];
    const float* ci2  = (const float*)d_in[10];
    float* out = (float*)d_out;

    char* ws = (char*)d_ws;
    u16*   h2p  = (u16*)(ws + 4718592);
    u16*   W1A  = (u16*)(ws + 24387584);
    u16*   W2A  = (u16*)(ws + 24518656);
    float* gl1  = (float*)(ws + 25698304);
    u32*   gl2u = (u32*)(ws + 25796608);

    k_gl1  <<<288, 256, 0, stream>>>(x, gl1, (u32*)h2p, gl2u);
    k_gate1<<<64,  256, 0, stream>>>(gl1, ce1, gd1, gd21, ci1, w1, W1A);
    k_gemm1<<<768, 256, 0, stream>>>(W1A, x, h2p, gl2u);
    k_gate2<<<64,  256, 0, stream>>>(gl2u, ce2, gd2, gd22, ci2, w2, W2A);
    k_conv2<<<768, 256, 0, stream>>>(W2A, h2p, out);
}